// Round 9
// baseline (1500.224 us; speedup 1.0000x reference)
//
#include <hip/hip_runtime.h>
#include <cstddef>

#define Bsz 2
#define Tt  2048
#define HIDc 2048
#define Hh  16
#define Kc  128
#define Dc  2048
#define BT  (Bsz*Tt)
#define TS  16

typedef __attribute__((ext_vector_type(8))) __bf16 bf16x8;
typedef __attribute__((ext_vector_type(4))) __bf16 bf16x4;
typedef __attribute__((ext_vector_type(4))) float f32x4;

// ---------------------------------------------------------------------------
// epilogue modes: 0 = none, 1 = decay (exp(-exp(A_log)*softplus(z+dt_bias))),
//                 2 = sigmoid
// ---------------------------------------------------------------------------
__device__ __forceinline__ float epilogue(float vacc, int c, int mode,
                                          const float* __restrict__ alog,
                                          const float* __restrict__ dtb) {
    if (mode == 1) {
        float z  = vacc + dtb[c];
        float sp = fmaxf(z, 0.f) + log1pf(expf(-fabsf(z)));
        return expf(-expf(alog[c >> 7]) * sp);
    } else if (mode == 2) {
        return 1.f / (1.f + expf(-vacc));
    }
    return vacc;
}

// ---------------------------------------------------------------------------
// bf16 MFMA GEMM: C[M,N] = A[M,K] @ Bw[N,K]^T.  A,Bw bf16 row-major, C f32.
// 128x128 tile, 4 waves (2x2), BK=64.  1024 16B-chunks per matrix ->
// 4 rounds x 256 threads.  LDS dest linear, source pre-swizzled with
// involution kc ^= (row&7); ds_read applies the same involution.
// ---------------------------------------------------------------------------
__global__ __launch_bounds__(256) void gemm_bf16_mfma(
    const __bf16* __restrict__ A, const __bf16* __restrict__ Bw,
    float* __restrict__ C, int M, int N, int K)
{
    __shared__ __bf16 As[128 * 64];
    __shared__ __bf16 Bs[128 * 64];
    const int tid = threadIdx.x;
    const int lane = tid & 63;
    const int wave = tid >> 6;
    const int wr = wave >> 1, wc = wave & 1;
    const int l15 = lane & 15, g = lane >> 4;
    const int row0 = blockIdx.y * 128, col0 = blockIdx.x * 128;

    f32x4 acc[4][4];
#pragma unroll
    for (int m = 0; m < 4; m++)
#pragma unroll
        for (int n = 0; n < 4; n++)
            acc[m][n] = (f32x4){0.f, 0.f, 0.f, 0.f};

    for (int k0 = 0; k0 < K; k0 += 64) {
        __syncthreads();
#pragma unroll
        for (int i = 0; i < 4; i++) {
            const int c = i * 256 + tid;           // chunk id 0..1023
            const int row = c >> 3, kc = c & 7;
            const int scol = k0 + 8 * (kc ^ (row & 7));
            __builtin_amdgcn_global_load_lds(
                (const __attribute__((address_space(1))) void*)(A + (size_t)(row0 + row) * K + scol),
                (__attribute__((address_space(3))) void*)(As + (size_t)(i * 256 + (tid & ~63)) * 8),
                16, 0, 0);
        }
#pragma unroll
        for (int i = 0; i < 4; i++) {
            const int c = i * 256 + tid;
            const int row = c >> 3, kc = c & 7;
            const int scol = k0 + 8 * (kc ^ (row & 7));
            __builtin_amdgcn_global_load_lds(
                (const __attribute__((address_space(1))) void*)(Bw + (size_t)(col0 + row) * K + scol),
                (__attribute__((address_space(3))) void*)(Bs + (size_t)(i * 256 + (tid & ~63)) * 8),
                16, 0, 0);
        }
        __syncthreads();
#pragma unroll
        for (int ks = 0; ks < 2; ks++) {
            bf16x8 af[4], bfr[4];
#pragma unroll
            for (int m = 0; m < 4; m++) {
                const int row = wr * 64 + m * 16 + l15;
                const int kc = ks * 4 + g;
                af[m] = *(const bf16x8*)(As + row * 64 + 8 * (kc ^ (row & 7)));
            }
#pragma unroll
            for (int n = 0; n < 4; n++) {
                const int col = wc * 64 + n * 16 + l15;
                const int kc = ks * 4 + g;
                bfr[n] = *(const bf16x8*)(Bs + col * 64 + 8 * (kc ^ (col & 7)));
            }
#pragma unroll
            for (int m = 0; m < 4; m++)
#pragma unroll
                for (int n = 0; n < 4; n++)
                    acc[m][n] = __builtin_amdgcn_mfma_f32_16x16x32_bf16(
                        af[m], bfr[n], acc[m][n], 0, 0, 0);
        }
    }
#pragma unroll
    for (int m = 0; m < 4; m++) {
        const int rbase = row0 + wr * 64 + m * 16 + g * 4;
#pragma unroll
        for (int n = 0; n < 4; n++) {
            const int col = col0 + wc * 64 + n * 16 + l15;
#pragma unroll
            for (int r = 0; r < 4; r++)
                C[(size_t)(rbase + r) * N + col] = acc[m][n][r];
        }
    }
}

// f32 -> bf16 elementwise (4 per thread)
__global__ __launch_bounds__(256) void cvt_bf16(
    const float* __restrict__ in, __bf16* __restrict__ o)
{
    const int i = blockIdx.x * 256 + threadIdx.x;
    float4 v = *(const float4*)(in + (size_t)4 * i);
    bf16x4 r;
    r[0] = (__bf16)v.x; r[1] = (__bf16)v.y; r[2] = (__bf16)v.z; r[3] = (__bf16)v.w;
    *(bf16x4*)(o + (size_t)4 * i) = r;
}

// W[K,N] f32 -> WT[N,K] bf16
__global__ __launch_bounds__(256) void transpose_to_bf16(
    const float* __restrict__ W, __bf16* __restrict__ WT, int Kd, int N)
{
    __shared__ float tile[32][33];
    const int n0 = blockIdx.x * 32, k0 = blockIdx.y * 32;
    const int tx = threadIdx.x & 31, ty = threadIdx.x >> 5;
#pragma unroll
    for (int i = 0; i < 4; i++)
        tile[ty + 8 * i][tx] = W[(size_t)(k0 + ty + 8 * i) * N + n0 + tx];
    __syncthreads();
#pragma unroll
    for (int i = 0; i < 4; i++)
        WT[(size_t)(n0 + ty + 8 * i) * Kd + k0 + tx] = (__bf16)tile[tx][ty + 8 * i];
}

// ---------------------------------------------------------------------------
// f32 GEMM (kept for skinny/mid mats): C[M,N] = A[M,Kd] @ B[Kd,N].
// ---------------------------------------------------------------------------
__global__ __launch_bounds__(256) void gemm_f32(
    const float* __restrict__ A, const float* __restrict__ B, float* __restrict__ C,
    int M, int N, int Kd, int mode,
    const float* __restrict__ alog, const float* __restrict__ dtb)
{
    __shared__ float As[8][128];
    __shared__ float Bs[8][128];
    const int tid = threadIdx.x;
    const int tx = tid & 15, ty = tid >> 4;
    const int rbase = blockIdx.y * 128, cbase = blockIdx.x * 128;
    const int z = blockIdx.z, Znum = gridDim.z;
    const int kchunk = Kd / Znum;
    const int kbeg = z * kchunk, kend = kbeg + kchunk;

    float acc[8][8];
#pragma unroll
    for (int i = 0; i < 8; i++)
#pragma unroll
        for (int j = 0; j < 8; j++) acc[i][j] = 0.f;

    const int arow = tid >> 1, ak = (tid & 1) << 2;
    const int bk = tid >> 5, bn = (tid & 31) << 2;

    for (int k0 = kbeg; k0 < kend; k0 += 8) {
        float4 av = *(const float4*)(A + (size_t)(rbase + arow) * Kd + (k0 + ak));
        float4 bv = make_float4(0.f, 0.f, 0.f, 0.f);
        if (cbase + bn < N)
            bv = *(const float4*)(B + (size_t)(k0 + bk) * N + (cbase + bn));
        __syncthreads();
        As[ak + 0][arow] = av.x;
        As[ak + 1][arow] = av.y;
        As[ak + 2][arow] = av.z;
        As[ak + 3][arow] = av.w;
        *(float4*)(&Bs[bk][bn]) = bv;
        __syncthreads();
#pragma unroll
        for (int kk = 0; kk < 8; ++kk) {
            float a[8], bb[8];
            *(float4*)(&a[0]) = *(const float4*)(&As[kk][ty << 2]);
            *(float4*)(&a[4]) = *(const float4*)(&As[kk][64 + (ty << 2)]);
            *(float4*)(&bb[0]) = *(const float4*)(&Bs[kk][tx << 2]);
            *(float4*)(&bb[4]) = *(const float4*)(&Bs[kk][64 + (tx << 2)]);
#pragma unroll
            for (int i = 0; i < 8; i++)
#pragma unroll
                for (int j = 0; j < 8; j++)
                    acc[i][j] = fmaf(a[i], bb[j], acc[i][j]);
        }
    }

    if (Znum > 1) {
        float* P = C + (size_t)z * M * N;
#pragma unroll
        for (int ih = 0; ih < 2; ih++)
#pragma unroll
            for (int i = 0; i < 4; i++) {
                int r = rbase + ih * 64 + (ty << 2) + i;
#pragma unroll
                for (int jh = 0; jh < 2; jh++) {
                    int c0 = cbase + jh * 64 + (tx << 2);
                    if (c0 < N) {
                        float4 vv;
                        vv.x = acc[ih * 4 + i][jh * 4 + 0];
                        vv.y = acc[ih * 4 + i][jh * 4 + 1];
                        vv.z = acc[ih * 4 + i][jh * 4 + 2];
                        vv.w = acc[ih * 4 + i][jh * 4 + 3];
                        *(float4*)(P + (size_t)r * N + c0) = vv;
                    }
                }
            }
    } else {
#pragma unroll
        for (int ih = 0; ih < 2; ih++)
#pragma unroll
            for (int i = 0; i < 4; i++) {
                int r = rbase + ih * 64 + (ty << 2) + i;
#pragma unroll
                for (int jh = 0; jh < 2; jh++) {
                    int c0 = cbase + jh * 64 + (tx << 2);
                    if (c0 < N) {
                        float4 vv;
                        vv.x = epilogue(acc[ih * 4 + i][jh * 4 + 0], c0 + 0, mode, alog, dtb);
                        vv.y = epilogue(acc[ih * 4 + i][jh * 4 + 1], c0 + 1, mode, alog, dtb);
                        vv.z = epilogue(acc[ih * 4 + i][jh * 4 + 2], c0 + 2, mode, alog, dtb);
                        vv.w = epilogue(acc[ih * 4 + i][jh * 4 + 3], c0 + 3, mode, alog, dtb);
                        *(float4*)(C + (size_t)r * N + c0) = vv;
                    }
                }
            }
    }
}

// split-K reduce: out[i] = epilogue(sum_z part[z][i])
__global__ __launch_bounds__(256) void reduce_k(
    const float* __restrict__ part, float* __restrict__ out,
    int MN, int Z, int N, int mode,
    const float* __restrict__ alog, const float* __restrict__ dtb)
{
    int i = blockIdx.x * 256 + threadIdx.x;
    if (i < MN) {
        float s = 0.f;
        for (int zz = 0; zz < Z; zz++) s += part[(size_t)zz * MN + i];
        out[i] = epilogue(s, i % N, mode, alog, dtb);
    }
}

// ---------------------------------------------------------------------------
// causal depthwise conv (KC=4) + SiLU, optional l2norm over 128-group.
// ---------------------------------------------------------------------------
__global__ __launch_bounds__(128) void conv_silu_norm(
    const float* __restrict__ pre, const float* __restrict__ cw,
    const float* __restrict__ cb, float* __restrict__ out, int mode)
{
    const int bid = blockIdx.x;
    const int h = bid & (Hh - 1);
    const int bt = bid >> 4;
    const int t = bt & (Tt - 1);
    const int lane = threadIdx.x;
    const int col = h * Kc + lane;
    const float w0 = cw[col * 4 + 0], w1 = cw[col * 4 + 1];
    const float w2 = cw[col * 4 + 2], w3 = cw[col * 4 + 3];
    const float* bp = pre + (size_t)bt * Dc + col;
    float acc = cb[col] + w3 * bp[0];
    if (t >= 1) acc += w2 * bp[-Dc];
    if (t >= 2) acc += w1 * bp[-2 * Dc];
    if (t >= 3) acc += w0 * bp[-3 * Dc];
    float val = acc / (1.f + expf(-acc));   // silu
    if (mode) {
        float ss = val * val;
#pragma unroll
        for (int m = 1; m < 64; m <<= 1) ss += __shfl_xor(ss, m);
        __shared__ float p2[2];
        if ((lane & 63) == 0) p2[lane >> 6] = ss;
        __syncthreads();
        float tot = p2[0] + p2[1];
        float r = rsqrtf(tot + 1e-6f);
        val *= r;
        if (mode == 2) val *= 0.08838834764831845f;  // 128^-0.5
    }
    out[(size_t)bt * Dc + col] = val;
}

// ---------------------------------------------------------------------------
// all-VALU cross-lane sum helpers
// ---------------------------------------------------------------------------
__device__ __forceinline__ float dpp_ror8(float v) {
    return __int_as_float(__builtin_amdgcn_update_dpp(
        0, __float_as_int(v), 0x128, 0xf, 0xf, true));
}

__device__ __forceinline__ float sum_x16(float v) {
#if __has_builtin(__builtin_amdgcn_permlane16_swap)
    auto r = __builtin_amdgcn_permlane16_swap(__float_as_uint(v), __float_as_uint(v),
                                              false, false);
    return __uint_as_float(r[0]) + __uint_as_float(r[1]);
#else
    return v + __shfl_xor(v, 16);
#endif
}

__device__ __forceinline__ float sum_x32(float v) {
#if __has_builtin(__builtin_amdgcn_permlane32_swap)
    auto r = __builtin_amdgcn_permlane32_swap(__float_as_uint(v), __float_as_uint(v),
                                              false, false);
    return __uint_as_float(r[0]) + __uint_as_float(r[1]);
#else
    return v + __shfl_xor(v, 32);
#endif
}

__device__ __forceinline__ void reduce3(float& a, float& b, float& c) {
    a += dpp_ror8(a);
    b += dpp_ror8(b);
    c += dpp_ror8(c);
    a = sum_x16(a);
    b = sum_x16(b);
    c = sum_x16(c);
    a = sum_x32(a);
    b = sum_x32(b);
    c = sum_x32(c);
}

__device__ __forceinline__ float kda_step(
    const float4 cq[4], const float4 ck[4], const float4 cd[4],
    float cv, float cbt, float S[16])
{
    float kv0 = 0.f, kv1 = 0.f, qs0 = 0.f, qs1 = 0.f, qk0 = 0.f, qk1 = 0.f;
#pragma unroll
    for (int i = 0; i < 4; i++) {
        S[4 * i + 0] *= cd[i].x;
        S[4 * i + 1] *= cd[i].y;
        S[4 * i + 2] *= cd[i].z;
        S[4 * i + 3] *= cd[i].w;
        kv0 = fmaf(ck[i].x, S[4 * i + 0], kv0);
        kv1 = fmaf(ck[i].y, S[4 * i + 1], kv1);
        kv0 = fmaf(ck[i].z, S[4 * i + 2], kv0);
        kv1 = fmaf(ck[i].w, S[4 * i + 3], kv1);
        qs0 = fmaf(cq[i].x, S[4 * i + 0], qs0);
        qs1 = fmaf(cq[i].y, S[4 * i + 1], qs1);
        qs0 = fmaf(cq[i].z, S[4 * i + 2], qs0);
        qs1 = fmaf(cq[i].w, S[4 * i + 3], qs1);
        qk0 = fmaf(ck[i].x, cq[i].x, qk0);
        qk1 = fmaf(ck[i].y, cq[i].y, qk1);
        qk0 = fmaf(ck[i].z, cq[i].z, qk0);
        qk1 = fmaf(ck[i].w, cq[i].w, qk1);
    }
    float kv = kv0 + kv1, qs = qs0 + qs1, qk = qk0 + qk1;
    reduce3(kv, qs, qk);
    float vd = (cv - kv) * cbt;
    float ov = fmaf(qk, vd, qs);
#pragma unroll
    for (int i = 0; i < 4; i++) {
        S[4 * i + 0] = fmaf(ck[i].x, vd, S[4 * i + 0]);
        S[4 * i + 1] = fmaf(ck[i].y, vd, S[4 * i + 1]);
        S[4 * i + 2] = fmaf(ck[i].z, vd, S[4 * i + 2]);
        S[4 * i + 3] = fmaf(ck[i].w, vd, S[4 * i + 3]);
    }
    return ov;
}

// ---------------------------------------------------------------------------
// KDA gated delta-rule scan, LDS-tiled (TS=16 steps/tile, double-buffered).
// 1 wave/block, grid 512, XCD-swizzled decode.
// __launch_bounds__(64,1): unlock full VGPR budget so the staged tile
// (26 float4) stays LIVE across the step loop -> loads issue at tile start,
// vmcnt waits land at tile end (~4800 cyc later).  R8's VGPR_Count=88
// proved the compiler had sunk the loads (register starvation).
// LDS per matrix: [8 kq-blocks][TS*16 + 4 pad] -> kq-stride 260 floats ->
// bank offset 4 per block -> conflict-free step ds_reads.
// ---------------------------------------------------------------------------
__global__ __launch_bounds__(64, 1) void kda_scan_kernel(
    const float* __restrict__ q, const float* __restrict__ k,
    const float* __restrict__ v, const float* __restrict__ dec,
    const float* __restrict__ beta, float* __restrict__ o)
{
    __shared__ float qkd[2][3][8][TS * 16 + 4];
    __shared__ float vls[2][TS * 8];
    __shared__ float bls[2][TS];

    const int bid = blockIdx.x;
    const int r8 = bid & 7;
    const int s = bid >> 3;
    const int bh = r8 + 8 * (s >> 4);   // bijective over [0,32)
    const int vc = s & 15;
    const int h = bh & (Hh - 1);
    const int b = bh >> 4;
    const int lane = threadIdx.x;
    const int vloc = lane & 7;
    const int kq = lane >> 3;
    const size_t base = ((size_t)b * Tt) * Dc + h * Kc;
    const size_t bbase = ((size_t)b * Tt) * Hh + h;

    // staging geometry: chunk c = r*64+lane, r=0..7 ->
    //   t  = (r&1)*8 + ((lane&31)>>2)   (0..15)
    //   kb = 2*(r>>1) + (lane>>5)       (0..7)
    //   c4 = lane&3
    const int st_ = (lane & 31) >> 2;
    const int skb = lane >> 5;
    const int sc4 = lane & 3;
    const int vt = lane >> 1, vcc = lane & 1;  // v staging (lane<32)

    float S[16];
#pragma unroll
    for (int i = 0; i < 16; i++) S[i] = 0.f;

    float4 stq[8], stk[8], std_[8], stv;
    float stb;

#define STAGE_LOAD(TILE)                                                        \
    {                                                                           \
        _Pragma("unroll")                                                       \
        for (int r = 0; r < 8; r++) {                                           \
            const int t = (r & 1) * 8 + st_;                                    \
            const int kb = 2 * (r >> 1) + skb;                                  \
            const size_t rb = base + (size_t)((TILE) * TS + t) * Dc;            \
            stq[r]  = *(const float4*)(q   + rb + kb * 16 + sc4 * 4);           \
            stk[r]  = *(const float4*)(k   + rb + kb * 16 + sc4 * 4);           \
            std_[r] = *(const float4*)(dec + rb + kb * 16 + sc4 * 4);           \
        }                                                                       \
        if (lane < 32)                                                          \
            stv = *(const float4*)(v + base + (size_t)((TILE) * TS + vt) * Dc   \
                                   + vc * 8 + vcc * 4);                         \
        if (lane < TS)                                                          \
            stb = beta[bbase + (size_t)((TILE) * TS + lane) * Hh];              \
    }

#define STAGE_WRITE(BUF)                                                        \
    {                                                                           \
        _Pragma("unroll")                                                       \
        for (int r = 0; r < 8; r++) {                                           \
            const int t = (r & 1) * 8 + st_;                                    \
            const int kb = 2 * (r >> 1) + skb;                                  \
            *(float4*)&qkd[BUF][0][kb][t * 16 + sc4 * 4] = stq[r];              \
            *(float4*)&qkd[BUF][1][kb][t * 16 + sc4 * 4] = stk[r];              \
            *(float4*)&qkd[BUF][2][kb][t * 16 + sc4 * 4] = std_[r];             \
        }                                                                       \
        if (lane < 32) *(float4*)&vls[BUF][vt * 8 + vcc * 4] = stv;             \
        if (lane < TS) bls[BUF][lane] = stb;                                    \
    }

    STAGE_LOAD(0);
    STAGE_WRITE(0);

    const int NT = Tt / TS;   // 128
    for (int tile = 0; tile < NT; ++tile) {
        const int buf = tile & 1;
        if (tile + 1 < NT) STAGE_LOAD(tile + 1);
#pragma unroll
        for (int t = 0; t < TS; ++t) {
            float4 cq[4], ck[4], cd[4];
#pragma unroll
            for (int i = 0; i < 4; i++) {
                cq[i] = *(const float4*)&qkd[buf][0][kq][t * 16 + i * 4];
                ck[i] = *(const float4*)&qkd[buf][1][kq][t * 16 + i * 4];
                cd[i] = *(const float4*)&qkd[buf][2][kq][t * 16 + i * 4];
            }
            const float cv = vls[buf][t * 8 + vloc];
            const float cbt = bls[buf][t];
            const float ov = kda_step(cq, ck, cd, cv, cbt, S);
            if (lane < 8)
                o[base + (size_t)(tile * TS + t) * Dc + vc * 8 + lane] = ov;
        }
        if (tile + 1 < NT) STAGE_WRITE(buf ^ 1);
    }
#undef STAGE_LOAD
#undef STAGE_WRITE
}

// ---------------------------------------------------------------------------
// gated head-wise RMSNorm
// ---------------------------------------------------------------------------
__global__ __launch_bounds__(128) void post_norm(
    const float* __restrict__ o, const float* __restrict__ gate,
    const float* __restrict__ onw, float* __restrict__ og)
{
    const int bid = blockIdx.x;
    const int h = bid & (Hh - 1);
    const int bt = bid >> 4;
    const int lane = threadIdx.x;
    size_t idx = (size_t)bt * Dc + h * Kc + lane;
    float ov = o[idx];
    float ss = ov * ov;
#pragma unroll
    for (int m = 1; m < 64; m <<= 1) ss += __shfl_xor(ss, m);
    __shared__ float p2[2];
    if ((lane & 63) == 0) p2[lane >> 6] = ss;
    __syncthreads();
    float var = (p2[0] + p2[1]) * (1.f / 128.f);
    float r = rsqrtf(var + 1e-5f);
    float gt = gate[idx];
    og[idx] = ov * r * onw[lane] * (1.f / (1.f + expf(-gt)));
}

// ---------------------------------------------------------------------------
extern "C" void kernel_launch(void* const* d_in, const int* in_sizes, int n_in,
                              void* d_out, int out_size, void* d_ws, size_t ws_size,
                              hipStream_t stream) {
    const float* x        = (const float*)d_in[0];
    const float* Wq       = (const float*)d_in[1];
    const float* Wk       = (const float*)d_in[2];
    const float* Wv       = (const float*)d_in[3];
    const float* conv_q_w = (const float*)d_in[4];
    const float* conv_q_b = (const float*)d_in[5];
    const float* conv_k_w = (const float*)d_in[6];
    const float* conv_k_b = (const float*)d_in[7];
    const float* conv_v_w = (const float*)d_in[8];
    const float* conv_v_b = (const float*)d_in[9];
    const float* Wfa      = (const float*)d_in[10];
    const float* Wfb      = (const float*)d_in[11];
    const float* A_log    = (const float*)d_in[12];
    const float* dt_bias  = (const float*)d_in[13];
    const float* Wb       = (const float*)d_in[14];
    const float* Wga      = (const float*)d_in[15];
    const float* Wgb      = (const float*)d_in[16];
    const float* o_norm_w = (const float*)d_in[17];
    const float* Wo       = (const float*)d_in[18];
    float* out = (float*)d_out;

    float* ws = (float*)d_ws;
    const size_t SZ = (size_t)BT * Dc;      // 8.39M floats
    float* bufA = ws + 0 * SZ;   // qpre -> k
    float* bufB = ws + 1 * SZ;   // kpre -> v
    float* bufC = ws + 2 * SZ;   // vpre -> o
    float* bufG = ws + 3 * SZ;   // decay -> og
    float* bufQ = ws + 4 * SZ;   // q
    float* bufI = ws + 5 * SZ;   // splitK partials, then gate
    float* fa   = ws + 6 * SZ;            // BT*128
    float* ga   = fa + (size_t)BT * Kc;   // BT*128
    float* beta = ga + (size_t)BT * Kc;   // BT*16
    __bf16* xb = (__bf16*)(beta + (size_t)BT * Hh);   // BT*Dc bf16 (reused for og)
    __bf16* wT = xb + SZ;                             // HIDc*Dc bf16

    dim3 blk(256);
    // 0: x -> bf16
    cvt_bf16<<<dim3(SZ / 1024), blk, 0, stream>>>(x, xb);
    dim3 tgrid(Dc / 32, HIDc / 32);
    dim3 gbig(Dc / 128, BT / 128);
    // 1-3: big projections (bf16 MFMA), transpose each weight just-in-time
    transpose_to_bf16<<<tgrid, blk, 0, stream>>>(Wq, wT, HIDc, Dc);
    gemm_bf16_mfma<<<gbig, blk, 0, stream>>>(xb, wT, bufA, BT, Dc, HIDc);
    transpose_to_bf16<<<tgrid, blk, 0, stream>>>(Wk, wT, HIDc, Dc);
    gemm_bf16_mfma<<<gbig, blk, 0, stream>>>(xb, wT, bufB, BT, Dc, HIDc);
    transpose_to_bf16<<<tgrid, blk, 0, stream>>>(Wv, wT, HIDc, Dc);
    gemm_bf16_mfma<<<gbig, blk, 0, stream>>>(xb, wT, bufC, BT, Dc, HIDc);
    // 4-6: skinny projections with split-K (f32)
    dim3 gskin(1, 32, 8);
    gemm_f32<<<gskin, blk, 0, stream>>>(x, Wfa, bufI, BT, Kc, HIDc, 0, nullptr, nullptr);
    reduce_k<<<dim3((BT * Kc + 255) / 256), blk, 0, stream>>>(bufI, fa, BT * Kc, 8, Kc, 0, nullptr, nullptr);
    gemm_f32<<<gskin, blk, 0, stream>>>(x, Wga, bufI, BT, Kc, HIDc, 0, nullptr, nullptr);
    reduce_k<<<dim3((BT * Kc + 255) / 256), blk, 0, stream>>>(bufI, ga, BT * Kc, 8, Kc, 0, nullptr, nullptr);
    gemm_f32<<<gskin, blk, 0, stream>>>(x, Wb, bufI, BT, Hh, HIDc, 0, nullptr, nullptr);
    reduce_k<<<dim3((BT * Hh + 255) / 256), blk, 0, stream>>>(bufI, beta, BT * Hh, 8, Hh, 2, nullptr, nullptr);
    // 7: decay; 8: gate (f32, K=128)
    dim3 gmid(Dc / 128, BT / 128);
    gemm_f32<<<gmid, blk, 0, stream>>>(fa, Wfb, bufG, BT, Dc, Kc, 1, A_log, dt_bias);
    gemm_f32<<<gmid, blk, 0, stream>>>(ga, Wgb, bufI, BT, Dc, Kc, 0, nullptr, nullptr);
    // 9-11: conv + silu (+ l2norm)
    dim3 cblk(128);
    dim3 cgrid(BT * Hh);
    conv_silu_norm<<<cgrid, cblk, 0, stream>>>(bufA, conv_q_w, conv_q_b, bufQ, 2);
    conv_silu_norm<<<cgrid, cblk, 0, stream>>>(bufB, conv_k_w, conv_k_b, bufA, 1);
    conv_silu_norm<<<cgrid, cblk, 0, stream>>>(bufC, conv_v_w, conv_v_b, bufB, 0);
    // 12: scan  (q=bufQ, k=bufA, v=bufB, dec=bufG, beta -> o=bufC)
    kda_scan_kernel<<<dim3(512), dim3(64), 0, stream>>>(bufQ, bufA, bufB, bufG, beta, bufC);
    // 13: gated RMSNorm -> og = bufG
    post_norm<<<cgrid, cblk, 0, stream>>>(bufC, bufI, o_norm_w, bufG);
    // 14: out = og @ Wo (bf16 MFMA); og -> bf16 reusing xb
    transpose_to_bf16<<<tgrid, blk, 0, stream>>>(Wo, wT, Dc, HIDc);
    cvt_bf16<<<dim3(SZ / 1024), blk, 0, stream>>>(bufG, xb);
    dim3 gout(HIDc / 128, BT / 128);
    gemm_bf16_mfma<<<gout, blk, 0, stream>>>(xb, wT, out, BT, HIDc, Dc);
}

// Round 10
// 1272.863 us; speedup vs baseline: 1.1786x; 1.1786x over previous
//
#include <hip/hip_runtime.h>
#include <cstddef>

#define Bsz 2
#define Tt  2048
#define HIDc 2048
#define Hh  16
#define Kc  128
#define Dc  2048
#define BT  (Bsz*Tt)
#define TS  16

typedef __attribute__((ext_vector_type(8))) __bf16 bf16x8;
typedef __attribute__((ext_vector_type(4))) __bf16 bf16x4;
typedef __attribute__((ext_vector_type(4))) float f32x4;

// ---------------------------------------------------------------------------
// epilogue modes: 0 = none, 1 = decay (exp(-exp(A_log)*softplus(z+dt_bias))),
//                 2 = sigmoid
// ---------------------------------------------------------------------------
__device__ __forceinline__ float epilogue(float vacc, int c, int mode,
                                          const float* __restrict__ alog,
                                          const float* __restrict__ dtb) {
    if (mode == 1) {
        float z  = vacc + dtb[c];
        float sp = fmaxf(z, 0.f) + log1pf(expf(-fabsf(z)));
        return expf(-expf(alog[c >> 7]) * sp);
    } else if (mode == 2) {
        return 1.f / (1.f + expf(-vacc));
    }
    return vacc;
}

// ---------------------------------------------------------------------------
// bf16 MFMA GEMM: C[M,N] = A[M,K] @ Bw[N,K]^T.  A,Bw bf16 row-major, C f32.
// 128x128 tile, 4 waves (2x2), BK=64.  1024 16B-chunks per matrix ->
// 4 rounds x 256 threads.  LDS dest linear, source pre-swizzled with
// involution kc ^= (row&7); ds_read applies the same involution.
// ---------------------------------------------------------------------------
__global__ __launch_bounds__(256) void gemm_bf16_mfma(
    const __bf16* __restrict__ A, const __bf16* __restrict__ Bw,
    float* __restrict__ C, int M, int N, int K)
{
    __shared__ __bf16 As[128 * 64];
    __shared__ __bf16 Bs[128 * 64];
    const int tid = threadIdx.x;
    const int lane = tid & 63;
    const int wave = tid >> 6;
    const int wr = wave >> 1, wc = wave & 1;
    const int l15 = lane & 15, g = lane >> 4;
    const int row0 = blockIdx.y * 128, col0 = blockIdx.x * 128;

    f32x4 acc[4][4];
#pragma unroll
    for (int m = 0; m < 4; m++)
#pragma unroll
        for (int n = 0; n < 4; n++)
            acc[m][n] = (f32x4){0.f, 0.f, 0.f, 0.f};

    for (int k0 = 0; k0 < K; k0 += 64) {
        __syncthreads();
#pragma unroll
        for (int i = 0; i < 4; i++) {
            const int c = i * 256 + tid;           // chunk id 0..1023
            const int row = c >> 3, kc = c & 7;
            const int scol = k0 + 8 * (kc ^ (row & 7));
            __builtin_amdgcn_global_load_lds(
                (const __attribute__((address_space(1))) void*)(A + (size_t)(row0 + row) * K + scol),
                (__attribute__((address_space(3))) void*)(As + (size_t)(i * 256 + (tid & ~63)) * 8),
                16, 0, 0);
        }
#pragma unroll
        for (int i = 0; i < 4; i++) {
            const int c = i * 256 + tid;
            const int row = c >> 3, kc = c & 7;
            const int scol = k0 + 8 * (kc ^ (row & 7));
            __builtin_amdgcn_global_load_lds(
                (const __attribute__((address_space(1))) void*)(Bw + (size_t)(col0 + row) * K + scol),
                (__attribute__((address_space(3))) void*)(Bs + (size_t)(i * 256 + (tid & ~63)) * 8),
                16, 0, 0);
        }
        __syncthreads();
#pragma unroll
        for (int ks = 0; ks < 2; ks++) {
            bf16x8 af[4], bfr[4];
#pragma unroll
            for (int m = 0; m < 4; m++) {
                const int row = wr * 64 + m * 16 + l15;
                const int kc = ks * 4 + g;
                af[m] = *(const bf16x8*)(As + row * 64 + 8 * (kc ^ (row & 7)));
            }
#pragma unroll
            for (int n = 0; n < 4; n++) {
                const int col = wc * 64 + n * 16 + l15;
                const int kc = ks * 4 + g;
                bfr[n] = *(const bf16x8*)(Bs + col * 64 + 8 * (kc ^ (col & 7)));
            }
#pragma unroll
            for (int m = 0; m < 4; m++)
#pragma unroll
                for (int n = 0; n < 4; n++)
                    acc[m][n] = __builtin_amdgcn_mfma_f32_16x16x32_bf16(
                        af[m], bfr[n], acc[m][n], 0, 0, 0);
        }
    }
#pragma unroll
    for (int m = 0; m < 4; m++) {
        const int rbase = row0 + wr * 64 + m * 16 + g * 4;
#pragma unroll
        for (int n = 0; n < 4; n++) {
            const int col = col0 + wc * 64 + n * 16 + l15;
#pragma unroll
            for (int r = 0; r < 4; r++)
                C[(size_t)(rbase + r) * N + col] = acc[m][n][r];
        }
    }
}

// f32 -> bf16 elementwise (4 per thread)
__global__ __launch_bounds__(256) void cvt_bf16(
    const float* __restrict__ in, __bf16* __restrict__ o)
{
    const int i = blockIdx.x * 256 + threadIdx.x;
    float4 v = *(const float4*)(in + (size_t)4 * i);
    bf16x4 r;
    r[0] = (__bf16)v.x; r[1] = (__bf16)v.y; r[2] = (__bf16)v.z; r[3] = (__bf16)v.w;
    *(bf16x4*)(o + (size_t)4 * i) = r;
}

// W[K,N] f32 -> WT[N,K] bf16
__global__ __launch_bounds__(256) void transpose_to_bf16(
    const float* __restrict__ W, __bf16* __restrict__ WT, int Kd, int N)
{
    __shared__ float tile[32][33];
    const int n0 = blockIdx.x * 32, k0 = blockIdx.y * 32;
    const int tx = threadIdx.x & 31, ty = threadIdx.x >> 5;
#pragma unroll
    for (int i = 0; i < 4; i++)
        tile[ty + 8 * i][tx] = W[(size_t)(k0 + ty + 8 * i) * N + n0 + tx];
    __syncthreads();
#pragma unroll
    for (int i = 0; i < 4; i++)
        WT[(size_t)(n0 + ty + 8 * i) * Kd + k0 + tx] = (__bf16)tile[tx][ty + 8 * i];
}

// ---------------------------------------------------------------------------
// f32 GEMM (kept for skinny/mid mats): C[M,N] = A[M,Kd] @ B[Kd,N].
// ---------------------------------------------------------------------------
__global__ __launch_bounds__(256) void gemm_f32(
    const float* __restrict__ A, const float* __restrict__ B, float* __restrict__ C,
    int M, int N, int Kd, int mode,
    const float* __restrict__ alog, const float* __restrict__ dtb)
{
    __shared__ float As[8][128];
    __shared__ float Bs[8][128];
    const int tid = threadIdx.x;
    const int tx = tid & 15, ty = tid >> 4;
    const int rbase = blockIdx.y * 128, cbase = blockIdx.x * 128;
    const int z = blockIdx.z, Znum = gridDim.z;
    const int kchunk = Kd / Znum;
    const int kbeg = z * kchunk, kend = kbeg + kchunk;

    float acc[8][8];
#pragma unroll
    for (int i = 0; i < 8; i++)
#pragma unroll
        for (int j = 0; j < 8; j++) acc[i][j] = 0.f;

    const int arow = tid >> 1, ak = (tid & 1) << 2;
    const int bk = tid >> 5, bn = (tid & 31) << 2;

    for (int k0 = kbeg; k0 < kend; k0 += 8) {
        float4 av = *(const float4*)(A + (size_t)(rbase + arow) * Kd + (k0 + ak));
        float4 bv = make_float4(0.f, 0.f, 0.f, 0.f);
        if (cbase + bn < N)
            bv = *(const float4*)(B + (size_t)(k0 + bk) * N + (cbase + bn));
        __syncthreads();
        As[ak + 0][arow] = av.x;
        As[ak + 1][arow] = av.y;
        As[ak + 2][arow] = av.z;
        As[ak + 3][arow] = av.w;
        *(float4*)(&Bs[bk][bn]) = bv;
        __syncthreads();
#pragma unroll
        for (int kk = 0; kk < 8; ++kk) {
            float a[8], bb[8];
            *(float4*)(&a[0]) = *(const float4*)(&As[kk][ty << 2]);
            *(float4*)(&a[4]) = *(const float4*)(&As[kk][64 + (ty << 2)]);
            *(float4*)(&bb[0]) = *(const float4*)(&Bs[kk][tx << 2]);
            *(float4*)(&bb[4]) = *(const float4*)(&Bs[kk][64 + (tx << 2)]);
#pragma unroll
            for (int i = 0; i < 8; i++)
#pragma unroll
                for (int j = 0; j < 8; j++)
                    acc[i][j] = fmaf(a[i], bb[j], acc[i][j]);
        }
    }

    if (Znum > 1) {
        float* P = C + (size_t)z * M * N;
#pragma unroll
        for (int ih = 0; ih < 2; ih++)
#pragma unroll
            for (int i = 0; i < 4; i++) {
                int r = rbase + ih * 64 + (ty << 2) + i;
#pragma unroll
                for (int jh = 0; jh < 2; jh++) {
                    int c0 = cbase + jh * 64 + (tx << 2);
                    if (c0 < N) {
                        float4 vv;
                        vv.x = acc[ih * 4 + i][jh * 4 + 0];
                        vv.y = acc[ih * 4 + i][jh * 4 + 1];
                        vv.z = acc[ih * 4 + i][jh * 4 + 2];
                        vv.w = acc[ih * 4 + i][jh * 4 + 3];
                        *(float4*)(P + (size_t)r * N + c0) = vv;
                    }
                }
            }
    } else {
#pragma unroll
        for (int ih = 0; ih < 2; ih++)
#pragma unroll
            for (int i = 0; i < 4; i++) {
                int r = rbase + ih * 64 + (ty << 2) + i;
#pragma unroll
                for (int jh = 0; jh < 2; jh++) {
                    int c0 = cbase + jh * 64 + (tx << 2);
                    if (c0 < N) {
                        float4 vv;
                        vv.x = epilogue(acc[ih * 4 + i][jh * 4 + 0], c0 + 0, mode, alog, dtb);
                        vv.y = epilogue(acc[ih * 4 + i][jh * 4 + 1], c0 + 1, mode, alog, dtb);
                        vv.z = epilogue(acc[ih * 4 + i][jh * 4 + 2], c0 + 2, mode, alog, dtb);
                        vv.w = epilogue(acc[ih * 4 + i][jh * 4 + 3], c0 + 3, mode, alog, dtb);
                        *(float4*)(C + (size_t)r * N + c0) = vv;
                    }
                }
            }
    }
}

// split-K reduce: out[i] = epilogue(sum_z part[z][i])
__global__ __launch_bounds__(256) void reduce_k(
    const float* __restrict__ part, float* __restrict__ out,
    int MN, int Z, int N, int mode,
    const float* __restrict__ alog, const float* __restrict__ dtb)
{
    int i = blockIdx.x * 256 + threadIdx.x;
    if (i < MN) {
        float s = 0.f;
        for (int zz = 0; zz < Z; zz++) s += part[(size_t)zz * MN + i];
        out[i] = epilogue(s, i % N, mode, alog, dtb);
    }
}

// ---------------------------------------------------------------------------
// causal depthwise conv (KC=4) + SiLU, optional l2norm over 128-group.
// ---------------------------------------------------------------------------
__global__ __launch_bounds__(128) void conv_silu_norm(
    const float* __restrict__ pre, const float* __restrict__ cw,
    const float* __restrict__ cb, float* __restrict__ out, int mode)
{
    const int bid = blockIdx.x;
    const int h = bid & (Hh - 1);
    const int bt = bid >> 4;
    const int t = bt & (Tt - 1);
    const int lane = threadIdx.x;
    const int col = h * Kc + lane;
    const float w0 = cw[col * 4 + 0], w1 = cw[col * 4 + 1];
    const float w2 = cw[col * 4 + 2], w3 = cw[col * 4 + 3];
    const float* bp = pre + (size_t)bt * Dc + col;
    float acc = cb[col] + w3 * bp[0];
    if (t >= 1) acc += w2 * bp[-Dc];
    if (t >= 2) acc += w1 * bp[-2 * Dc];
    if (t >= 3) acc += w0 * bp[-3 * Dc];
    float val = acc / (1.f + expf(-acc));   // silu
    if (mode) {
        float ss = val * val;
#pragma unroll
        for (int m = 1; m < 64; m <<= 1) ss += __shfl_xor(ss, m);
        __shared__ float p2[2];
        if ((lane & 63) == 0) p2[lane >> 6] = ss;
        __syncthreads();
        float tot = p2[0] + p2[1];
        float r = rsqrtf(tot + 1e-6f);
        val *= r;
        if (mode == 2) val *= 0.08838834764831845f;  // 128^-0.5
    }
    out[(size_t)bt * Dc + col] = val;
}

// ---------------------------------------------------------------------------
// all-VALU cross-lane sum helpers
// ---------------------------------------------------------------------------
__device__ __forceinline__ float dpp_ror8(float v) {
    return __int_as_float(__builtin_amdgcn_update_dpp(
        0, __float_as_int(v), 0x128, 0xf, 0xf, true));
}

__device__ __forceinline__ float sum_x16(float v) {
#if __has_builtin(__builtin_amdgcn_permlane16_swap)
    auto r = __builtin_amdgcn_permlane16_swap(__float_as_uint(v), __float_as_uint(v),
                                              false, false);
    return __uint_as_float(r[0]) + __uint_as_float(r[1]);
#else
    return v + __shfl_xor(v, 16);
#endif
}

__device__ __forceinline__ float sum_x32(float v) {
#if __has_builtin(__builtin_amdgcn_permlane32_swap)
    auto r = __builtin_amdgcn_permlane32_swap(__float_as_uint(v), __float_as_uint(v),
                                              false, false);
    return __uint_as_float(r[0]) + __uint_as_float(r[1]);
#else
    return v + __shfl_xor(v, 32);
#endif
}

__device__ __forceinline__ void reduce3(float& a, float& b, float& c) {
    a += dpp_ror8(a);
    b += dpp_ror8(b);
    c += dpp_ror8(c);
    a = sum_x16(a);
    b = sum_x16(b);
    c = sum_x16(c);
    a = sum_x32(a);
    b = sum_x32(b);
    c = sum_x32(c);
}

__device__ __forceinline__ float kda_step(
    const float4 cq[4], const float4 ck[4], const float4 cd[4],
    float cv, float cbt, float S[16])
{
    float kv0 = 0.f, kv1 = 0.f, qs0 = 0.f, qs1 = 0.f, qk0 = 0.f, qk1 = 0.f;
#pragma unroll
    for (int i = 0; i < 4; i++) {
        S[4 * i + 0] *= cd[i].x;
        S[4 * i + 1] *= cd[i].y;
        S[4 * i + 2] *= cd[i].z;
        S[4 * i + 3] *= cd[i].w;
        kv0 = fmaf(ck[i].x, S[4 * i + 0], kv0);
        kv1 = fmaf(ck[i].y, S[4 * i + 1], kv1);
        kv0 = fmaf(ck[i].z, S[4 * i + 2], kv0);
        kv1 = fmaf(ck[i].w, S[4 * i + 3], kv1);
        qs0 = fmaf(cq[i].x, S[4 * i + 0], qs0);
        qs1 = fmaf(cq[i].y, S[4 * i + 1], qs1);
        qs0 = fmaf(cq[i].z, S[4 * i + 2], qs0);
        qs1 = fmaf(cq[i].w, S[4 * i + 3], qs1);
        qk0 = fmaf(ck[i].x, cq[i].x, qk0);
        qk1 = fmaf(ck[i].y, cq[i].y, qk1);
        qk0 = fmaf(ck[i].z, cq[i].z, qk0);
        qk1 = fmaf(ck[i].w, cq[i].w, qk1);
    }
    float kv = kv0 + kv1, qs = qs0 + qs1, qk = qk0 + qk1;
    reduce3(kv, qs, qk);
    float vd = (cv - kv) * cbt;
    float ov = fmaf(qk, vd, qs);
#pragma unroll
    for (int i = 0; i < 4; i++) {
        S[4 * i + 0] = fmaf(ck[i].x, vd, S[4 * i + 0]);
        S[4 * i + 1] = fmaf(ck[i].y, vd, S[4 * i + 1]);
        S[4 * i + 2] = fmaf(ck[i].z, vd, S[4 * i + 2]);
        S[4 * i + 3] = fmaf(ck[i].w, vd, S[4 * i + 3]);
    }
    return ov;
}

// compute TS steps from one staged LDS buffer
__device__ __forceinline__ void kda_tile(
    const float (&sm)[3][TS * 128], const float (&vm)[TS * 8],
    const float (&bm)[TS], float S[16], int kq, int vloc,
    float* __restrict__ op, int lane)
{
#pragma unroll
    for (int t = 0; t < TS; ++t) {
        float4 cq[4], ck[4], cd[4];
#pragma unroll
        for (int i = 0; i < 4; i++) {
            cq[i] = *(const float4*)&sm[0][t * 128 + 32 * i + 4 * kq];
            ck[i] = *(const float4*)&sm[1][t * 128 + 32 * i + 4 * kq];
            cd[i] = *(const float4*)&sm[2][t * 128 + 32 * i + 4 * kq];
        }
        const float ov = kda_step(cq, ck, cd, vm[t * 8 + vloc], bm[t], S);
        if (lane < 8)
            op[(size_t)t * Dc + lane] = ov;
    }
}

// ---------------------------------------------------------------------------
// KDA gated delta-rule scan: global_load_lds-staged, TS=16 double-buffer.
// 1 wave/block, grid 512, XCD-swizzled decode.
// Staging uses direct global->LDS DMA (zero VGPR cost — R9's register
// staging spilled to scratch: WRITE_SIZE 430 MB).  LDS dest is linear in
// chunk order; the per-lane GLOBAL source realizes the permutation
// w = (kc&7)*4 + (kc>>3), so step reads at offset 32i+4kq hit 8 distinct
// bank groups (conflict-free) and broadcast within each kq group.
// Two distinct __shared__ buffers + manual 2x unroll let alias analysis
// keep STAGE(next) loads in flight across compute(cur); explicit
// s_waitcnt vmcnt(0) + sched_barrier at each half boundary.
// ---------------------------------------------------------------------------
__global__ __launch_bounds__(64) void kda_scan_kernel(
    const float* __restrict__ q, const float* __restrict__ k,
    const float* __restrict__ v, const float* __restrict__ dec,
    const float* __restrict__ beta, float* __restrict__ o)
{
    __shared__ float sA[3][TS * 128];
    __shared__ float sB[3][TS * 128];
    __shared__ float vA[TS * 8], vB[TS * 8];
    __shared__ float bA[TS], bB[TS];

    const int bid = blockIdx.x;
    const int r8 = bid & 7;
    const int s = bid >> 3;
    const int bh = r8 + 8 * (s >> 4);   // bijective over [0,32)
    const int vc = s & 15;
    const int h = bh & (Hh - 1);
    const int b = bh >> 4;
    const int lane = threadIdx.x;
    const int vloc = lane & 7;
    const int kq = lane >> 3;
    const size_t base = ((size_t)b * Tt) * Dc + h * Kc;
    const size_t bbase = ((size_t)b * Tt) * Hh + h;

    float S[16];
#pragma unroll
    for (int i = 0; i < 16; i++) S[i] = 0.f;

    // staging: chunk c = r*64 + lane; t = c>>5 = 2r + (lane>>5); kc = lane&31;
    // source col-chunk w = (kc&7)*4 + (kc>>3)
    const int s_t = lane >> 5;
    const int s_w = ((lane & 7) << 2) + ((lane & 31) >> 3);

#define STAGE(TILE, SM, VM, BM)                                                 \
    {                                                                           \
        _Pragma("unroll")                                                       \
        for (int r = 0; r < 8; r++) {                                           \
            const size_t rb = base + (size_t)((TILE) * TS + 2 * r + s_t) * Dc   \
                              + s_w * 4;                                        \
            __builtin_amdgcn_global_load_lds(                                   \
                (const __attribute__((address_space(1))) void*)(q + rb),        \
                (__attribute__((address_space(3))) void*)(&SM[0][r * 256]),     \
                16, 0, 0);                                                      \
            __builtin_amdgcn_global_load_lds(                                   \
                (const __attribute__((address_space(1))) void*)(k + rb),        \
                (__attribute__((address_space(3))) void*)(&SM[1][r * 256]),     \
                16, 0, 0);                                                      \
            __builtin_amdgcn_global_load_lds(                                   \
                (const __attribute__((address_space(1))) void*)(dec + rb),      \
                (__attribute__((address_space(3))) void*)(&SM[2][r * 256]),     \
                16, 0, 0);                                                      \
        }                                                                       \
        if (lane < 32)                                                          \
            __builtin_amdgcn_global_load_lds(                                   \
                (const __attribute__((address_space(1))) void*)(v + base        \
                    + (size_t)((TILE) * TS + (lane >> 1)) * Dc + vc * 8         \
                    + (lane & 1) * 4),                                          \
                (__attribute__((address_space(3))) void*)(&VM[0]), 16, 0, 0);   \
        if (lane < TS)                                                          \
            __builtin_amdgcn_global_load_lds(                                   \
                (const __attribute__((address_space(1))) void*)(beta + bbase    \
                    + (size_t)((TILE) * TS + lane) * Hh),                       \
                (__attribute__((address_space(3))) void*)(&BM[0]), 4, 0, 0);    \
    }

    STAGE(0, sA, vA, bA);
    asm volatile("s_waitcnt vmcnt(0)" ::: "memory");
    __builtin_amdgcn_sched_barrier(0);

    const int NT = Tt / TS;   // 128 (even)
    for (int tile = 0; tile < NT; tile += 2) {
        if (tile + 1 < NT) STAGE(tile + 1, sB, vB, bB);
        kda_tile(sA, vA, bA, S, kq, vloc,
                 o + base + (size_t)tile * TS * Dc + vc * 8, lane);
        asm volatile("s_waitcnt vmcnt(0)" ::: "memory");
        __builtin_amdgcn_sched_barrier(0);
        if (tile + 2 < NT) STAGE(tile + 2, sA, vA, bA);
        kda_tile(sB, vB, bB, S, kq, vloc,
                 o + base + (size_t)(tile + 1) * TS * Dc + vc * 8, lane);
        asm volatile("s_waitcnt vmcnt(0)" ::: "memory");
        __builtin_amdgcn_sched_barrier(0);
    }
#undef STAGE
}

// ---------------------------------------------------------------------------
// gated head-wise RMSNorm
// ---------------------------------------------------------------------------
__global__ __launch_bounds__(128) void post_norm(
    const float* __restrict__ o, const float* __restrict__ gate,
    const float* __restrict__ onw, float* __restrict__ og)
{
    const int bid = blockIdx.x;
    const int h = bid & (Hh - 1);
    const int bt = bid >> 4;
    const int lane = threadIdx.x;
    size_t idx = (size_t)bt * Dc + h * Kc + lane;
    float ov = o[idx];
    float ss = ov * ov;
#pragma unroll
    for (int m = 1; m < 64; m <<= 1) ss += __shfl_xor(ss, m);
    __shared__ float p2[2];
    if ((lane & 63) == 0) p2[lane >> 6] = ss;
    __syncthreads();
    float var = (p2[0] + p2[1]) * (1.f / 128.f);
    float r = rsqrtf(var + 1e-5f);
    float gt = gate[idx];
    og[idx] = ov * r * onw[lane] * (1.f / (1.f + expf(-gt)));
}

// ---------------------------------------------------------------------------
extern "C" void kernel_launch(void* const* d_in, const int* in_sizes, int n_in,
                              void* d_out, int out_size, void* d_ws, size_t ws_size,
                              hipStream_t stream) {
    const float* x        = (const float*)d_in[0];
    const float* Wq       = (const float*)d_in[1];
    const float* Wk       = (const float*)d_in[2];
    const float* Wv       = (const float*)d_in[3];
    const float* conv_q_w = (const float*)d_in[4];
    const float* conv_q_b = (const float*)d_in[5];
    const float* conv_k_w = (const float*)d_in[6];
    const float* conv_k_b = (const float*)d_in[7];
    const float* conv_v_w = (const float*)d_in[8];
    const float* conv_v_b = (const float*)d_in[9];
    const float* Wfa      = (const float*)d_in[10];
    const float* Wfb      = (const float*)d_in[11];
    const float* A_log    = (const float*)d_in[12];
    const float* dt_bias  = (const float*)d_in[13];
    const float* Wb       = (const float*)d_in[14];
    const float* Wga      = (const float*)d_in[15];
    const float* Wgb      = (const float*)d_in[16];
    const float* o_norm_w = (const float*)d_in[17];
    const float* Wo       = (const float*)d_in[18];
    float* out = (float*)d_out;

    float* ws = (float*)d_ws;
    const size_t SZ = (size_t)BT * Dc;      // 8.39M floats
    float* bufA = ws + 0 * SZ;   // qpre -> k
    float* bufB = ws + 1 * SZ;   // kpre -> v
    float* bufC = ws + 2 * SZ;   // vpre -> o
    float* bufG = ws + 3 * SZ;   // decay -> og
    float* bufQ = ws + 4 * SZ;   // q
    float* bufI = ws + 5 * SZ;   // splitK partials, then gate
    float* fa   = ws + 6 * SZ;            // BT*128
    float* ga   = fa + (size_t)BT * Kc;   // BT*128
    float* beta = ga + (size_t)BT * Kc;   // BT*16
    __bf16* xb = (__bf16*)(beta + (size_t)BT * Hh);   // BT*Dc bf16 (reused for og)
    __bf16* wT = xb + SZ;                             // HIDc*Dc bf16

    dim3 blk(256);
    // 0: x -> bf16
    cvt_bf16<<<dim3(SZ / 1024), blk, 0, stream>>>(x, xb);
    dim3 tgrid(Dc / 32, HIDc / 32);
    dim3 gbig(Dc / 128, BT / 128);
    // 1-3: big projections (bf16 MFMA), transpose each weight just-in-time
    transpose_to_bf16<<<tgrid, blk, 0, stream>>>(Wq, wT, HIDc, Dc);
    gemm_bf16_mfma<<<gbig, blk, 0, stream>>>(xb, wT, bufA, BT, Dc, HIDc);
    transpose_to_bf16<<<tgrid, blk, 0, stream>>>(Wk, wT, HIDc, Dc);
    gemm_bf16_mfma<<<gbig, blk, 0, stream>>>(xb, wT, bufB, BT, Dc, HIDc);
    transpose_to_bf16<<<tgrid, blk, 0, stream>>>(Wv, wT, HIDc, Dc);
    gemm_bf16_mfma<<<gbig, blk, 0, stream>>>(xb, wT, bufC, BT, Dc, HIDc);
    // 4-6: skinny projections with split-K (f32)
    dim3 gskin(1, 32, 8);
    gemm_f32<<<gskin, blk, 0, stream>>>(x, Wfa, bufI, BT, Kc, HIDc, 0, nullptr, nullptr);
    reduce_k<<<dim3((BT * Kc + 255) / 256), blk, 0, stream>>>(bufI, fa, BT * Kc, 8, Kc, 0, nullptr, nullptr);
    gemm_f32<<<gskin, blk, 0, stream>>>(x, Wga, bufI, BT, Kc, HIDc, 0, nullptr, nullptr);
    reduce_k<<<dim3((BT * Kc + 255) / 256), blk, 0, stream>>>(bufI, ga, BT * Kc, 8, Kc, 0, nullptr, nullptr);
    gemm_f32<<<gskin, blk, 0, stream>>>(x, Wb, bufI, BT, Hh, HIDc, 0, nullptr, nullptr);
    reduce_k<<<dim3((BT * Hh + 255) / 256), blk, 0, stream>>>(bufI, beta, BT * Hh, 8, Hh, 2, nullptr, nullptr);
    // 7: decay; 8: gate (f32, K=128)
    dim3 gmid(Dc / 128, BT / 128);
    gemm_f32<<<gmid, blk, 0, stream>>>(fa, Wfb, bufG, BT, Dc, Kc, 1, A_log, dt_bias);
    gemm_f32<<<gmid, blk, 0, stream>>>(ga, Wgb, bufI, BT, Dc, Kc, 0, nullptr, nullptr);
    // 9-11: conv + silu (+ l2norm)
    dim3 cblk(128);
    dim3 cgrid(BT * Hh);
    conv_silu_norm<<<cgrid, cblk, 0, stream>>>(bufA, conv_q_w, conv_q_b, bufQ, 2);
    conv_silu_norm<<<cgrid, cblk, 0, stream>>>(bufB, conv_k_w, conv_k_b, bufA, 1);
    conv_silu_norm<<<cgrid, cblk, 0, stream>>>(bufC, conv_v_w, conv_v_b, bufB, 0);
    // 12: scan  (q=bufQ, k=bufA, v=bufB, dec=bufG, beta -> o=bufC)
    kda_scan_kernel<<<dim3(512), dim3(64), 0, stream>>>(bufQ, bufA, bufB, bufG, beta, bufC);
    // 13: gated RMSNorm -> og = bufG
    post_norm<<<cgrid, cblk, 0, stream>>>(bufC, bufI, o_norm_w, bufG);
    // 14: out = og @ Wo (bf16 MFMA); og -> bf16 reusing xb
    transpose_to_bf16<<<tgrid, blk, 0, stream>>>(Wo, wT, Dc, HIDc);
    cvt_bf16<<<dim3(SZ / 1024), blk, 0, stream>>>(bufG, xb);
    dim3 gout(HIDc / 128, BT / 128);
    gemm_bf16_mfma<<<gout, blk, 0, stream>>>(xb, wT, out, BT, HIDc, Dc);
}

// Round 12
// 1159.376 us; speedup vs baseline: 1.2940x; 1.0979x over previous
//
#include <hip/hip_runtime.h>
#include <cstddef>

#define Bsz 2
#define Tt  2048
#define HIDc 2048
#define Hh  16
#define Kc  128
#define Dc  2048
#define BT  (Bsz*Tt)
#define TS  8

typedef __attribute__((ext_vector_type(8))) __bf16 bf16x8;
typedef __attribute__((ext_vector_type(4))) __bf16 bf16x4;
typedef __attribute__((ext_vector_type(4))) float f32x4;

// ---------------------------------------------------------------------------
// epilogue modes: 0 = none, 1 = decay (exp(-exp(A_log)*softplus(z+dt_bias))),
//                 2 = sigmoid
// ---------------------------------------------------------------------------
__device__ __forceinline__ float epilogue(float vacc, int c, int mode,
                                          const float* __restrict__ alog,
                                          const float* __restrict__ dtb) {
    if (mode == 1) {
        float z  = vacc + dtb[c];
        float sp = fmaxf(z, 0.f) + log1pf(expf(-fabsf(z)));
        return expf(-expf(alog[c >> 7]) * sp);
    } else if (mode == 2) {
        return 1.f / (1.f + expf(-vacc));
    }
    return vacc;
}

// ---------------------------------------------------------------------------
// bf16 MFMA GEMM: C[M,N] = A[M,K] @ Bw[N,K]^T.  A,Bw bf16 row-major, C f32.
// 128x128 tile, 4 waves (2x2), BK=64.
// ---------------------------------------------------------------------------
__global__ __launch_bounds__(256) void gemm_bf16_mfma(
    const __bf16* __restrict__ A, const __bf16* __restrict__ Bw,
    float* __restrict__ C, int M, int N, int K)
{
    __shared__ __bf16 As[128 * 64];
    __shared__ __bf16 Bs[128 * 64];
    const int tid = threadIdx.x;
    const int lane = tid & 63;
    const int wave = tid >> 6;
    const int wr = wave >> 1, wc = wave & 1;
    const int l15 = lane & 15, g = lane >> 4;
    const int row0 = blockIdx.y * 128, col0 = blockIdx.x * 128;

    f32x4 acc[4][4];
#pragma unroll
    for (int m = 0; m < 4; m++)
#pragma unroll
        for (int n = 0; n < 4; n++)
            acc[m][n] = (f32x4){0.f, 0.f, 0.f, 0.f};

    for (int k0 = 0; k0 < K; k0 += 64) {
        __syncthreads();
#pragma unroll
        for (int i = 0; i < 4; i++) {
            const int c = i * 256 + tid;           // chunk id 0..1023
            const int row = c >> 3, kc = c & 7;
            const int scol = k0 + 8 * (kc ^ (row & 7));
            __builtin_amdgcn_global_load_lds(
                (const __attribute__((address_space(1))) void*)(A + (size_t)(row0 + row) * K + scol),
                (__attribute__((address_space(3))) void*)(As + (size_t)(i * 256 + (tid & ~63)) * 8),
                16, 0, 0);
        }
#pragma unroll
        for (int i = 0; i < 4; i++) {
            const int c = i * 256 + tid;
            const int row = c >> 3, kc = c & 7;
            const int scol = k0 + 8 * (kc ^ (row & 7));
            __builtin_amdgcn_global_load_lds(
                (const __attribute__((address_space(1))) void*)(Bw + (size_t)(col0 + row) * K + scol),
                (__attribute__((address_space(3))) void*)(Bs + (size_t)(i * 256 + (tid & ~63)) * 8),
                16, 0, 0);
        }
        __syncthreads();
#pragma unroll
        for (int ks = 0; ks < 2; ks++) {
            bf16x8 af[4], bfr[4];
#pragma unroll
            for (int m = 0; m < 4; m++) {
                const int row = wr * 64 + m * 16 + l15;
                const int kc = ks * 4 + g;
                af[m] = *(const bf16x8*)(As + row * 64 + 8 * (kc ^ (row & 7)));
            }
#pragma unroll
            for (int n = 0; n < 4; n++) {
                const int col = wc * 64 + n * 16 + l15;
                const int kc = ks * 4 + g;
                bfr[n] = *(const bf16x8*)(Bs + col * 64 + 8 * (kc ^ (col & 7)));
            }
#pragma unroll
            for (int m = 0; m < 4; m++)
#pragma unroll
                for (int n = 0; n < 4; n++)
                    acc[m][n] = __builtin_amdgcn_mfma_f32_16x16x32_bf16(
                        af[m], bfr[n], acc[m][n], 0, 0, 0);
        }
    }
#pragma unroll
    for (int m = 0; m < 4; m++) {
        const int rbase = row0 + wr * 64 + m * 16 + g * 4;
#pragma unroll
        for (int n = 0; n < 4; n++) {
            const int col = col0 + wc * 64 + n * 16 + l15;
#pragma unroll
            for (int r = 0; r < 4; r++)
                C[(size_t)(rbase + r) * N + col] = acc[m][n][r];
        }
    }
}

// f32 -> bf16 elementwise (4 per thread)
__global__ __launch_bounds__(256) void cvt_bf16(
    const float* __restrict__ in, __bf16* __restrict__ o)
{
    const int i = blockIdx.x * 256 + threadIdx.x;
    float4 v = *(const float4*)(in + (size_t)4 * i);
    bf16x4 r;
    r[0] = (__bf16)v.x; r[1] = (__bf16)v.y; r[2] = (__bf16)v.z; r[3] = (__bf16)v.w;
    *(bf16x4*)(o + (size_t)4 * i) = r;
}

// W[K,N] f32 -> WT[N,K] bf16
__global__ __launch_bounds__(256) void transpose_to_bf16(
    const float* __restrict__ W, __bf16* __restrict__ WT, int Kd, int N)
{
    __shared__ float tile[32][33];
    const int n0 = blockIdx.x * 32, k0 = blockIdx.y * 32;
    const int tx = threadIdx.x & 31, ty = threadIdx.x >> 5;
#pragma unroll
    for (int i = 0; i < 4; i++)
        tile[ty + 8 * i][tx] = W[(size_t)(k0 + ty + 8 * i) * N + n0 + tx];
    __syncthreads();
#pragma unroll
    for (int i = 0; i < 4; i++)
        WT[(size_t)(n0 + ty + 8 * i) * Kd + k0 + tx] = (__bf16)tile[tx][ty + 8 * i];
}

// ---------------------------------------------------------------------------
// f32 GEMM (kept for skinny/mid mats): C[M,N] = A[M,Kd] @ B[Kd,N].
// ---------------------------------------------------------------------------
__global__ __launch_bounds__(256) void gemm_f32(
    const float* __restrict__ A, const float* __restrict__ B, float* __restrict__ C,
    int M, int N, int Kd, int mode,
    const float* __restrict__ alog, const float* __restrict__ dtb)
{
    __shared__ float As[8][128];
    __shared__ float Bs[8][128];
    const int tid = threadIdx.x;
    const int tx = tid & 15, ty = tid >> 4;
    const int rbase = blockIdx.y * 128, cbase = blockIdx.x * 128;
    const int z = blockIdx.z, Znum = gridDim.z;
    const int kchunk = Kd / Znum;
    const int kbeg = z * kchunk, kend = kbeg + kchunk;

    float acc[8][8];
#pragma unroll
    for (int i = 0; i < 8; i++)
#pragma unroll
        for (int j = 0; j < 8; j++) acc[i][j] = 0.f;

    const int arow = tid >> 1, ak = (tid & 1) << 2;
    const int bk = tid >> 5, bn = (tid & 31) << 2;

    for (int k0 = kbeg; k0 < kend; k0 += 8) {
        float4 av = *(const float4*)(A + (size_t)(rbase + arow) * Kd + (k0 + ak));
        float4 bv = make_float4(0.f, 0.f, 0.f, 0.f);
        if (cbase + bn < N)
            bv = *(const float4*)(B + (size_t)(k0 + bk) * N + (cbase + bn));
        __syncthreads();
        As[ak + 0][arow] = av.x;
        As[ak + 1][arow] = av.y;
        As[ak + 2][arow] = av.z;
        As[ak + 3][arow] = av.w;
        *(float4*)(&Bs[bk][bn]) = bv;
        __syncthreads();
#pragma unroll
        for (int kk = 0; kk < 8; ++kk) {
            float a[8], bb[8];
            *(float4*)(&a[0]) = *(const float4*)(&As[kk][ty << 2]);
            *(float4*)(&a[4]) = *(const float4*)(&As[kk][64 + (ty << 2)]);
            *(float4*)(&bb[0]) = *(const float4*)(&Bs[kk][tx << 2]);
            *(float4*)(&bb[4]) = *(const float4*)(&Bs[kk][64 + (tx << 2)]);
#pragma unroll
            for (int i = 0; i < 8; i++)
#pragma unroll
                for (int j = 0; j < 8; j++)
                    acc[i][j] = fmaf(a[i], bb[j], acc[i][j]);
        }
    }

    if (Znum > 1) {
        float* P = C + (size_t)z * M * N;
#pragma unroll
        for (int ih = 0; ih < 2; ih++)
#pragma unroll
            for (int i = 0; i < 4; i++) {
                int r = rbase + ih * 64 + (ty << 2) + i;
#pragma unroll
                for (int jh = 0; jh < 2; jh++) {
                    int c0 = cbase + jh * 64 + (tx << 2);
                    if (c0 < N) {
                        float4 vv;
                        vv.x = acc[ih * 4 + i][jh * 4 + 0];
                        vv.y = acc[ih * 4 + i][jh * 4 + 1];
                        vv.z = acc[ih * 4 + i][jh * 4 + 2];
                        vv.w = acc[ih * 4 + i][jh * 4 + 3];
                        *(float4*)(P + (size_t)r * N + c0) = vv;
                    }
                }
            }
    } else {
#pragma unroll
        for (int ih = 0; ih < 2; ih++)
#pragma unroll
            for (int i = 0; i < 4; i++) {
                int r = rbase + ih * 64 + (ty << 2) + i;
#pragma unroll
                for (int jh = 0; jh < 2; jh++) {
                    int c0 = cbase + jh * 64 + (tx << 2);
                    if (c0 < N) {
                        float4 vv;
                        vv.x = epilogue(acc[ih * 4 + i][jh * 4 + 0], c0 + 0, mode, alog, dtb);
                        vv.y = epilogue(acc[ih * 4 + i][jh * 4 + 1], c0 + 1, mode, alog, dtb);
                        vv.z = epilogue(acc[ih * 4 + i][jh * 4 + 2], c0 + 2, mode, alog, dtb);
                        vv.w = epilogue(acc[ih * 4 + i][jh * 4 + 3], c0 + 3, mode, alog, dtb);
                        *(float4*)(C + (size_t)r * N + c0) = vv;
                    }
                }
            }
    }
}

// split-K reduce: out[i] = epilogue(sum_z part[z][i])
__global__ __launch_bounds__(256) void reduce_k(
    const float* __restrict__ part, float* __restrict__ out,
    int MN, int Z, int N, int mode,
    const float* __restrict__ alog, const float* __restrict__ dtb)
{
    int i = blockIdx.x * 256 + threadIdx.x;
    if (i < MN) {
        float s = 0.f;
        for (int zz = 0; zz < Z; zz++) s += part[(size_t)zz * MN + i];
        out[i] = epilogue(s, i % N, mode, alog, dtb);
    }
}

// ---------------------------------------------------------------------------
// causal depthwise conv (KC=4) + SiLU, optional l2norm over 128-group.
// ---------------------------------------------------------------------------
__global__ __launch_bounds__(128) void conv_silu_norm(
    const float* __restrict__ pre, const float* __restrict__ cw,
    const float* __restrict__ cb, float* __restrict__ out, int mode)
{
    const int bid = blockIdx.x;
    const int h = bid & (Hh - 1);
    const int bt = bid >> 4;
    const int t = bt & (Tt - 1);
    const int lane = threadIdx.x;
    const int col = h * Kc + lane;
    const float w0 = cw[col * 4 + 0], w1 = cw[col * 4 + 1];
    const float w2 = cw[col * 4 + 2], w3 = cw[col * 4 + 3];
    const float* bp = pre + (size_t)bt * Dc + col;
    float acc = cb[col] + w3 * bp[0];
    if (t >= 1) acc += w2 * bp[-Dc];
    if (t >= 2) acc += w1 * bp[-2 * Dc];
    if (t >= 3) acc += w0 * bp[-3 * Dc];
    float val = acc / (1.f + expf(-acc));   // silu
    if (mode) {
        float ss = val * val;
#pragma unroll
        for (int m = 1; m < 64; m <<= 1) ss += __shfl_xor(ss, m);
        __shared__ float p2[2];
        if ((lane & 63) == 0) p2[lane >> 6] = ss;
        __syncthreads();
        float tot = p2[0] + p2[1];
        float r = rsqrtf(tot + 1e-6f);
        val *= r;
        if (mode == 2) val *= 0.08838834764831845f;  // 128^-0.5
    }
    out[(size_t)bt * Dc + col] = val;
}

// ---------------------------------------------------------------------------
// DPP helpers: sum over lane strides 1,2,4,8 within each 16-lane row.
// ctrl must be a compile-time constant -> template parameter.
// ---------------------------------------------------------------------------
template <int CTRL>
__device__ __forceinline__ float dpp_add(float v) {
    return __int_as_float(__builtin_amdgcn_update_dpp(
        0, __float_as_int(v), CTRL, 0xf, 0xf, true));
}

__device__ __forceinline__ void reduce3_row(float& a, float& b, float& c) {
    a += dpp_add<0xB1>(a);    // quad_perm [1,0,3,2] : xor 1
    b += dpp_add<0xB1>(b);
    c += dpp_add<0xB1>(c);
    a += dpp_add<0x4E>(a);    // quad_perm [2,3,0,1] : xor 2
    b += dpp_add<0x4E>(b);
    c += dpp_add<0x4E>(c);
    a += dpp_add<0x124>(a);   // row_ror:4
    b += dpp_add<0x124>(b);
    c += dpp_add<0x124>(c);
    a += dpp_add<0x128>(a);   // row_ror:8
    b += dpp_add<0x128>(b);
    c += dpp_add<0x128>(c);
}

// ---------------------------------------------------------------------------
// KDA step, 8 k-elems per lane (kq = lane&15 over 16 groups; vloc = lane>>4).
// Each 16-lane row holds the FULL k-range for its v -> row-local reduction.
// ---------------------------------------------------------------------------
__device__ __forceinline__ float kda_step(
    const float4 cq[2], const float4 ck[2], const float4 cd[2],
    float cv, float cbt, float S[8])
{
    float kv0 = 0.f, kv1 = 0.f, qs0 = 0.f, qs1 = 0.f, qk0 = 0.f, qk1 = 0.f;
#pragma unroll
    for (int i = 0; i < 2; i++) {
        S[4 * i + 0] *= cd[i].x;
        S[4 * i + 1] *= cd[i].y;
        S[4 * i + 2] *= cd[i].z;
        S[4 * i + 3] *= cd[i].w;
        kv0 = fmaf(ck[i].x, S[4 * i + 0], kv0);
        kv1 = fmaf(ck[i].y, S[4 * i + 1], kv1);
        kv0 = fmaf(ck[i].z, S[4 * i + 2], kv0);
        kv1 = fmaf(ck[i].w, S[4 * i + 3], kv1);
        qs0 = fmaf(cq[i].x, S[4 * i + 0], qs0);
        qs1 = fmaf(cq[i].y, S[4 * i + 1], qs1);
        qs0 = fmaf(cq[i].z, S[4 * i + 2], qs0);
        qs1 = fmaf(cq[i].w, S[4 * i + 3], qs1);
        qk0 = fmaf(ck[i].x, cq[i].x, qk0);
        qk1 = fmaf(ck[i].y, cq[i].y, qk1);
        qk0 = fmaf(ck[i].z, cq[i].z, qk0);
        qk1 = fmaf(ck[i].w, cq[i].w, qk1);
    }
    float kv = kv0 + kv1, qs = qs0 + qs1, qk = qk0 + qk1;
    reduce3_row(kv, qs, qk);
    float vd = (cv - kv) * cbt;
    float ov = fmaf(qk, vd, qs);
#pragma unroll
    for (int i = 0; i < 2; i++) {
        S[4 * i + 0] = fmaf(ck[i].x, vd, S[4 * i + 0]);
        S[4 * i + 1] = fmaf(ck[i].y, vd, S[4 * i + 1]);
        S[4 * i + 2] = fmaf(ck[i].z, vd, S[4 * i + 2]);
        S[4 * i + 3] = fmaf(ck[i].w, vd, S[4 * i + 3]);
    }
    return ov;
}

// compute TS steps from one staged LDS buffer
__device__ __forceinline__ void kda_tile(
    const float (&sm)[3][TS * 128], const float (&vm)[TS * 4],
    const float (&bm)[TS], float S[8], int kq, int vloc,
    float* __restrict__ op, int lane)
{
#pragma unroll
    for (int t = 0; t < TS; ++t) {
        float4 cq[2], ck[2], cd[2];
#pragma unroll
        for (int i = 0; i < 2; i++) {
            cq[i] = *(const float4*)&sm[0][t * 128 + kq * 8 + i * 4];
            ck[i] = *(const float4*)&sm[1][t * 128 + kq * 8 + i * 4];
            cd[i] = *(const float4*)&sm[2][t * 128 + kq * 8 + i * 4];
        }
        const float ov = kda_step(cq, ck, cd, vm[t * 4 + vloc], bm[t], S);
        if ((lane & 15) == 0)
            op[(size_t)t * Dc + vloc] = ov;
    }
}

// ---------------------------------------------------------------------------
// KDA gated delta-rule scan: global_load_lds-staged, TS=8 double-buffer.
// Grid 1024 (v-chunk = 4): 4 blocks/CU -> 1 wave/SIMD (R10 had 0.5 —
// half the SIMDs idle; this is the latency-bound fix).
// Lane layout: vloc = lane>>4 (4 v across quarters), kq = lane&15
// (16 groups x 8 k).  Each 16-lane row holds the full k-range for its v,
// so reductions are row-local (strides 1..8, all DPP, no permlane).
// Staging is LINEAR (no permutation): step reads broadcast across rows,
// <=2-way bank aliasing (free).  XCD-grouped decode: all 32 v-blocks of a
// (b,h) share bid%8 -> one XCD's L2.
// ---------------------------------------------------------------------------
__global__ __launch_bounds__(64) void kda_scan_kernel(
    const float* __restrict__ q, const float* __restrict__ k,
    const float* __restrict__ v, const float* __restrict__ dec,
    const float* __restrict__ beta, float* __restrict__ o)
{
    __shared__ float sA[3][TS * 128];
    __shared__ float sB[3][TS * 128];
    __shared__ float vA[TS * 4], vB[TS * 4];
    __shared__ float bA[TS], bB[TS];

    const int bid = blockIdx.x;
    const int r8 = bid & 7;
    const int s = bid >> 3;                 // 0..127
    const int bh = r8 + 8 * (s >> 5);       // bijective over [0,32)
    const int vc = s & 31;                  // v-chunk of 4
    const int h = bh & (Hh - 1);
    const int b = bh >> 4;
    const int lane = threadIdx.x;
    const int vloc = lane >> 4;
    const int kq = lane & 15;
    const size_t base = ((size_t)b * Tt) * Dc + h * Kc;
    const size_t bbase = ((size_t)b * Tt) * Hh + h;

    float S[8];
#pragma unroll
    for (int i = 0; i < 8; i++) S[i] = 0.f;

    // staging: per matrix, chunk c = r*64 + lane (r=0..3);
    // t = c>>5 = 2r + (lane>>5), w = c&31 = lane&31 (float4 col)
    const int s_t = lane >> 5;
    const int s_w = lane & 31;

#define STAGE(TILE, SM, VM, BM)                                                 \
    {                                                                           \
        _Pragma("unroll")                                                       \
        for (int r = 0; r < 4; r++) {                                           \
            const size_t rb = base + (size_t)((TILE) * TS + 2 * r + s_t) * Dc   \
                              + s_w * 4;                                        \
            __builtin_amdgcn_global_load_lds(                                   \
                (const __attribute__((address_space(1))) void*)(q + rb),        \
                (__attribute__((address_space(3))) void*)(&SM[0][r * 256]),     \
                16, 0, 0);                                                      \
            __builtin_amdgcn_global_load_lds(                                   \
                (const __attribute__((address_space(1))) void*)(k + rb),        \
                (__attribute__((address_space(3))) void*)(&SM[1][r * 256]),     \
                16, 0, 0);                                                      \
            __builtin_amdgcn_global_load_lds(                                   \
                (const __attribute__((address_space(1))) void*)(dec + rb),      \
                (__attribute__((address_space(3))) void*)(&SM[2][r * 256]),     \
                16, 0, 0);                                                      \
        }                                                                       \
        if (lane < TS)                                                          \
            __builtin_amdgcn_global_load_lds(                                   \
                (const __attribute__((address_space(1))) void*)(v + base        \
                    + (size_t)((TILE) * TS + lane) * Dc + vc * 4),              \
                (__attribute__((address_space(3))) void*)(&VM[0]), 16, 0, 0);   \
        if (lane < TS)                                                          \
            __builtin_amdgcn_global_load_lds(                                   \
                (const __attribute__((address_space(1))) void*)(beta + bbase    \
                    + (size_t)((TILE) * TS + lane) * Hh),                       \
                (__attribute__((address_space(3))) void*)(&BM[0]), 4, 0, 0);    \
    }

    STAGE(0, sA, vA, bA);
    asm volatile("s_waitcnt vmcnt(0)" ::: "memory");
    __builtin_amdgcn_sched_barrier(0);

    const int NT = Tt / TS;   // 256 (even)
    for (int tile = 0; tile < NT; tile += 2) {
        if (tile + 1 < NT) STAGE(tile + 1, sB, vB, bB);
        kda_tile(sA, vA, bA, S, kq, vloc,
                 o + base + (size_t)tile * TS * Dc + vc * 4, lane);
        asm volatile("s_waitcnt vmcnt(0)" ::: "memory");
        __builtin_amdgcn_sched_barrier(0);
        if (tile + 2 < NT) STAGE(tile + 2, sA, vA, bA);
        kda_tile(sB, vB, bB, S, kq, vloc,
                 o + base + (size_t)(tile + 1) * TS * Dc + vc * 4, lane);
        asm volatile("s_waitcnt vmcnt(0)" ::: "memory");
        __builtin_amdgcn_sched_barrier(0);
    }
#undef STAGE
}

// ---------------------------------------------------------------------------
// gated head-wise RMSNorm
// ---------------------------------------------------------------------------
__global__ __launch_bounds__(128) void post_norm(
    const float* __restrict__ o, const float* __restrict__ gate,
    const float* __restrict__ onw, float* __restrict__ og)
{
    const int bid = blockIdx.x;
    const int h = bid & (Hh - 1);
    const int bt = bid >> 4;
    const int lane = threadIdx.x;
    size_t idx = (size_t)bt * Dc + h * Kc + lane;
    float ov = o[idx];
    float ss = ov * ov;
#pragma unroll
    for (int m = 1; m < 64; m <<= 1) ss += __shfl_xor(ss, m);
    __shared__ float p2[2];
    if ((lane & 63) == 0) p2[lane >> 6] = ss;
    __syncthreads();
    float var = (p2[0] + p2[1]) * (1.f / 128.f);
    float r = rsqrtf(var + 1e-5f);
    float gt = gate[idx];
    og[idx] = ov * r * onw[lane] * (1.f / (1.f + expf(-gt)));
}

// ---------------------------------------------------------------------------
extern "C" void kernel_launch(void* const* d_in, const int* in_sizes, int n_in,
                              void* d_out, int out_size, void* d_ws, size_t ws_size,
                              hipStream_t stream) {
    const float* x        = (const float*)d_in[0];
    const float* Wq       = (const float*)d_in[1];
    const float* Wk       = (const float*)d_in[2];
    const float* Wv       = (const float*)d_in[3];
    const float* conv_q_w = (const float*)d_in[4];
    const float* conv_q_b = (const float*)d_in[5];
    const float* conv_k_w = (const float*)d_in[6];
    const float* conv_k_b = (const float*)d_in[7];
    const float* conv_v_w = (const float*)d_in[8];
    const float* conv_v_b = (const float*)d_in[9];
    const float* Wfa      = (const float*)d_in[10];
    const float* Wfb      = (const float*)d_in[11];
    const float* A_log    = (const float*)d_in[12];
    const float* dt_bias  = (const float*)d_in[13];
    const float* Wb       = (const float*)d_in[14];
    const float* Wga      = (const float*)d_in[15];
    const float* Wgb      = (const float*)d_in[16];
    const float* o_norm_w = (const float*)d_in[17];
    const float* Wo       = (const float*)d_in[18];
    float* out = (float*)d_out;

    float* ws = (float*)d_ws;
    const size_t SZ = (size_t)BT * Dc;      // 8.39M floats
    float* bufA = ws + 0 * SZ;   // qpre -> k
    float* bufB = ws + 1 * SZ;   // kpre -> v
    float* bufC = ws + 2 * SZ;   // vpre -> o
    float* bufG = ws + 3 * SZ;   // decay -> og
    float* bufQ = ws + 4 * SZ;   // q
    float* bufI = ws + 5 * SZ;   // splitK partials, then gate
    float* fa   = ws + 6 * SZ;            // BT*128
    float* ga   = fa + (size_t)BT * Kc;   // BT*128
    float* beta = ga + (size_t)BT * Kc;   // BT*16
    __bf16* xb = (__bf16*)(beta + (size_t)BT * Hh);   // BT*Dc bf16 (reused for og)
    __bf16* wT = xb + SZ;                             // HIDc*Dc bf16

    dim3 blk(256);
    // 0: x -> bf16
    cvt_bf16<<<dim3(SZ / 1024), blk, 0, stream>>>(x, xb);
    dim3 tgrid(Dc / 32, HIDc / 32);
    dim3 gbig(Dc / 128, BT / 128);
    // 1-3: big projections (bf16 MFMA), transpose each weight just-in-time
    transpose_to_bf16<<<tgrid, blk, 0, stream>>>(Wq, wT, HIDc, Dc);
    gemm_bf16_mfma<<<gbig, blk, 0, stream>>>(xb, wT, bufA, BT, Dc, HIDc);
    transpose_to_bf16<<<tgrid, blk, 0, stream>>>(Wk, wT, HIDc, Dc);
    gemm_bf16_mfma<<<gbig, blk, 0, stream>>>(xb, wT, bufB, BT, Dc, HIDc);
    transpose_to_bf16<<<tgrid, blk, 0, stream>>>(Wv, wT, HIDc, Dc);
    gemm_bf16_mfma<<<gbig, blk, 0, stream>>>(xb, wT, bufC, BT, Dc, HIDc);
    // 4-6: skinny projections with split-K (f32)
    dim3 gskin(1, 32, 8);
    gemm_f32<<<gskin, blk, 0, stream>>>(x, Wfa, bufI, BT, Kc, HIDc, 0, nullptr, nullptr);
    reduce_k<<<dim3((BT * Kc + 255) / 256), blk, 0, stream>>>(bufI, fa, BT * Kc, 8, Kc, 0, nullptr, nullptr);
    gemm_f32<<<gskin, blk, 0, stream>>>(x, Wga, bufI, BT, Kc, HIDc, 0, nullptr, nullptr);
    reduce_k<<<dim3((BT * Kc + 255) / 256), blk, 0, stream>>>(bufI, ga, BT * Kc, 8, Kc, 0, nullptr, nullptr);
    gemm_f32<<<gskin, blk, 0, stream>>>(x, Wb, bufI, BT, Hh, HIDc, 0, nullptr, nullptr);
    reduce_k<<<dim3((BT * Hh + 255) / 256), blk, 0, stream>>>(bufI, beta, BT * Hh, 8, Hh, 2, nullptr, nullptr);
    // 7: decay; 8: gate (f32, K=128)
    dim3 gmid(Dc / 128, BT / 128);
    gemm_f32<<<gmid, blk, 0, stream>>>(fa, Wfb, bufG, BT, Dc, Kc, 1, A_log, dt_bias);
    gemm_f32<<<gmid, blk, 0, stream>>>(ga, Wgb, bufI, BT, Dc, Kc, 0, nullptr, nullptr);
    // 9-11: conv + silu (+ l2norm)
    dim3 cblk(128);
    dim3 cgrid(BT * Hh);
    conv_silu_norm<<<cgrid, cblk, 0, stream>>>(bufA, conv_q_w, conv_q_b, bufQ, 2);
    conv_silu_norm<<<cgrid, cblk, 0, stream>>>(bufB, conv_k_w, conv_k_b, bufA, 1);
    conv_silu_norm<<<cgrid, cblk, 0, stream>>>(bufC, conv_v_w, conv_v_b, bufB, 0);
    // 12: scan  (q=bufQ, k=bufA, v=bufB, dec=bufG, beta -> o=bufC)
    kda_scan_kernel<<<dim3(1024), dim3(64), 0, stream>>>(bufQ, bufA, bufB, bufG, beta, bufC);
    // 13: gated RMSNorm -> og = bufG
    post_norm<<<cgrid, cblk, 0, stream>>>(bufC, bufI, o_norm_w, bufG);
    // 14: out = og @ Wo (bf16 MFMA); og -> bf16 reusing xb
    transpose_to_bf16<<<tgrid, blk, 0, stream>>>(Wo, wT, Dc, HIDc);
    cvt_bf16<<<dim3(SZ / 1024), blk, 0, stream>>>(bufG, xb);
    dim3 gout(HIDc / 128, BT / 128);
    gemm_bf16_mfma<<<gout, blk, 0, stream>>>(xb, wT, out, BT, HIDc, Dc);
}